// Round 1
// baseline (4681.909 us; speedup 1.0000x reference)
//
#include <hip/hip_runtime.h>

#define NB 8
#define NN 8192
#define ND 256
#define NPOINT 2048
#define NSAMPLE 32
#define WNET 16
#define INCH 259          // 3 + 256
#define OUTCH 512
#define KPAD 4160         // 259*16 = 4144 padded to 4160 (= 65*64)

typedef short short8 __attribute__((ext_vector_type(8)));
typedef float float4v __attribute__((ext_vector_type(4)));

__device__ __forceinline__ unsigned short f2bf(float x){
  unsigned u = __float_as_uint(x);
  u = (u + 0x7FFFu + ((u >> 16) & 1u)) >> 16;
  return (unsigned short)u;
}
__device__ __forceinline__ float bf2f(unsigned short v){
  return __uint_as_float(((unsigned)v) << 16);
}

// ---------------------------------------------------------------------------
// 1. FPS: one block per batch. xyz in LDS (96KB), per-thread dists in regs.
//    Exact numpy arithmetic (no FMA contraction), argmax tie -> smallest idx.
// ---------------------------------------------------------------------------
__global__ __launch_bounds__(1024) void fps_kernel(const float* __restrict__ xyz,
    float* __restrict__ out0, float* __restrict__ out2, float* __restrict__ wnew){
#pragma clang fp contract(off)
  __shared__ float xs[NN], ys[NN], zs[NN];
  __shared__ float redv[16];
  __shared__ int   redi[16];
  const int b = blockIdx.x;
  const int t = threadIdx.x;
  const float* xp = xyz + (size_t)b * 3 * NN;
  float lx[8], ly[8], lz[8], ld[8];
#pragma unroll
  for (int j = 0; j < 8; j++){
    int n = t + j * 1024;
    float x = xp[n], y = xp[NN + n], z = xp[2 * NN + n];
    xs[n] = x; ys[n] = y; zs[n] = z;
    lx[j] = x; ly[j] = y; lz[j] = z; ld[j] = 1e10f;
  }
  __syncthreads();
  if (t == 0){
    out2[b * NPOINT] = 0.0f;
    out0[(size_t)b * 3 * NPOINT + 0]          = xs[0];
    out0[(size_t)b * 3 * NPOINT + NPOINT]     = ys[0];
    out0[(size_t)b * 3 * NPOINT + 2 * NPOINT] = zs[0];
    wnew[(size_t)b * NPOINT * 3 + 0] = xs[0];
    wnew[(size_t)b * NPOINT * 3 + 1] = ys[0];
    wnew[(size_t)b * NPOINT * 3 + 2] = zs[0];
  }
  int last = 0;
  for (int i = 1; i < NPOINT; i++){
    float cx = xs[last], cy = ys[last], cz = zs[last];
    float bv = -1.0f; int bi = 0;
#pragma unroll
    for (int j = 0; j < 8; j++){
      float dx = lx[j] - cx, dy = ly[j] - cy, dz = lz[j] - cz;
      float d  = (dx * dx + dy * dy) + dz * dz;   // numpy order, no fma
      float nd = fminf(ld[j], d);
      ld[j] = nd;
      if (nd > bv){ bv = nd; bi = t + j * 1024; }
    }
    // wave argmax (64 lanes), tie -> smaller index
#pragma unroll
    for (int off = 32; off > 0; off >>= 1){
      float ov = __shfl_down(bv, off, 64);
      int   oi = __shfl_down(bi, off, 64);
      if (ov > bv || (ov == bv && oi < bi)){ bv = ov; bi = oi; }
    }
    if ((t & 63) == 0){ redv[t >> 6] = bv; redi[t >> 6] = bi; }
    __syncthreads();
    { // every wave redundantly reduces the 16 per-wave winners (no 2nd barrier)
      int l = t & 63;
      float v2 = (l < 16) ? redv[l] : -2.0f;
      int   i2 = (l < 16) ? redi[l] : 0;
#pragma unroll
      for (int off = 8; off > 0; off >>= 1){
        float ov = __shfl_down(v2, off, 64);
        int   oi = __shfl_down(i2, off, 64);
        if (ov > v2 || (ov == v2 && oi < i2)){ v2 = ov; i2 = oi; }
      }
      last = __shfl(i2, 0, 64);
    }
    if (t == 0){
      out2[b * NPOINT + i] = (float)last;
      float cx2 = xs[last], cy2 = ys[last], cz2 = zs[last];
      out0[(size_t)b * 3 * NPOINT + i]              = cx2;
      out0[(size_t)b * 3 * NPOINT + NPOINT + i]     = cy2;
      out0[(size_t)b * 3 * NPOINT + 2 * NPOINT + i] = cz2;
      float* w = wnew + ((size_t)b * NPOINT + i) * 3;
      w[0] = cx2; w[1] = cy2; w[2] = cz2;
    }
    __syncthreads();   // protect redv/redi reuse next iteration
  }
}

// ---------------------------------------------------------------------------
// 2. transpose points [B,256,8192] f32 -> [B,8192,256] bf16
// ---------------------------------------------------------------------------
__global__ __launch_bounds__(1024) void transpose_points(
    const float* __restrict__ pts, unsigned short* __restrict__ ptsT){
  __shared__ float tile[64][65];
  const int b  = blockIdx.z;
  const int n0 = blockIdx.x * 64;
  const int d0 = blockIdx.y * 64;
  const int tx = threadIdx.x, ty = threadIdx.y;
  const float* src = pts + ((size_t)b * ND + d0) * NN + n0;
#pragma unroll
  for (int j = 0; j < 4; j++){
    int d = ty + j * 16;
    tile[d][tx] = src[(size_t)d * NN + tx];
  }
  __syncthreads();
  unsigned short* dst = ptsT + ((size_t)b * NN + n0) * ND + d0;
#pragma unroll
  for (int j = 0; j < 4; j++){
    int n = ty + j * 16;
    dst[(size_t)n * ND + tx] = f2bf(tile[tx][n]);
  }
}

// ---------------------------------------------------------------------------
// 3. lin_w [512,4144] f32 -> [512,4160] bf16 (pad zero)
// ---------------------------------------------------------------------------
__global__ __launch_bounds__(256) void convert_linw(
    const float* __restrict__ lw, unsigned short* __restrict__ out){
  int i = blockIdx.x * 256 + threadIdx.x;
  if (i >= OUTCH * KPAD) return;
  int o = i / KPAD, f = i - o * KPAD;
  float v = (f < WNET * INCH) ? lw[(size_t)o * (WNET * INCH) + f] : 0.f;
  out[i] = f2bf(v);
}

// ---------------------------------------------------------------------------
// 4. kNN: one 256-thread WG per query. radix-select rank-32 threshold,
//    stable (key,idx) tie-break for boundary elements.
// ---------------------------------------------------------------------------
__device__ __forceinline__ void find_bin64(const unsigned* hist, unsigned r,
                                           unsigned* outB, unsigned* outC, int lane){
  unsigned h0 = hist[lane * 4 + 0], h1 = hist[lane * 4 + 1];
  unsigned h2 = hist[lane * 4 + 2], h3 = hist[lane * 4 + 3];
  unsigned s4 = h0 + h1 + h2 + h3;
  unsigned sc = s4;
#pragma unroll
  for (int off = 1; off < 64; off <<= 1){
    unsigned o = __shfl_up(sc, off, 64);
    if (lane >= off) sc += o;
  }
  unsigned cum = sc - s4;
  if (cum < r && cum + h0 >= r){ *outB = lane * 4 + 0; *outC = cum; } cum += h0;
  if (cum < r && cum + h1 >= r){ *outB = lane * 4 + 1; *outC = cum; } cum += h1;
  if (cum < r && cum + h2 >= r){ *outB = lane * 4 + 2; *outC = cum; } cum += h2;
  if (cum < r && cum + h3 >= r){ *outB = lane * 4 + 3; *outC = cum; } cum += h3;
}

__global__ __launch_bounds__(256) void knn_kernel(const float* __restrict__ xyz,
    const float* __restrict__ newxyz, int* __restrict__ ws_idx){
  __shared__ unsigned key[NN];
  __shared__ unsigned hist[256];
  __shared__ int s_sel[48];
  __shared__ unsigned candk[256];
  __shared__ int candi[256];
  __shared__ int s_selcnt, s_candcnt;
  __shared__ unsigned s_info[4];   // B1, c0, B2, c1
  const int q = blockIdx.x;
  const int b = q >> 11;
  const int t = threadIdx.x;
  const float* xp = xyz + (size_t)b * 3 * NN;
  float qx = newxyz[q * 3], qy = newxyz[q * 3 + 1], qz = newxyz[q * 3 + 2];
  float qq = qx * qx + qy * qy + qz * qz;
#pragma unroll 4
  for (int j = 0; j < 32; j++){
    int n = t + j * 256;
    float px = xp[n], py = xp[NN + n], pz = xp[2 * NN + n];
    float pp = px * px + py * py + pz * pz;
    float d  = qq + pp - 2.f * (qx * px + qy * py + qz * pz);
    unsigned u = __float_as_uint(d);
    u ^= (u & 0x80000000u) ? 0xFFFFFFFFu : 0x80000000u;  // order-preserving
    key[n] = u;
  }
  hist[t] = 0;
  if (t == 0){ s_selcnt = 0; s_candcnt = 0; }
  __syncthreads();
#pragma unroll 4
  for (int j = 0; j < 32; j++){
    int n = t + j * 256;
    atomicAdd(&hist[key[n] >> 24], 1u);
  }
  __syncthreads();
  if (t < 64) find_bin64(hist, NSAMPLE, &s_info[0], &s_info[1], t);
  __syncthreads();
  unsigned B1 = s_info[0], c0 = s_info[1];
  hist[t] = 0;
  __syncthreads();
#pragma unroll 4
  for (int j = 0; j < 32; j++){
    int n = t + j * 256;
    unsigned u = key[n];
    if ((u >> 24) == B1) atomicAdd(&hist[(u >> 16) & 0xFFu], 1u);
  }
  __syncthreads();
  if (t < 64) find_bin64(hist, NSAMPLE - c0, &s_info[2], &s_info[3], t);
  __syncthreads();
  unsigned T16 = (B1 << 8) | s_info[2];
  int c01 = (int)(c0 + s_info[3]);       // count strictly below threshold (< 32)
#pragma unroll 4
  for (int j = 0; j < 32; j++){
    int n = t + j * 256;
    unsigned k16 = key[n] >> 16;
    if (k16 < T16){
      int p = atomicAdd(&s_selcnt, 1);
      s_sel[p] = n;
    } else if (k16 == T16){
      int p = atomicAdd(&s_candcnt, 1);
      if (p < 256){ candk[p] = key[n]; candi[p] = n; }
    }
  }
  __syncthreads();
  const int m = NSAMPLE - c01;           // >= 1 by construction
  const int L = s_candcnt;
  if (t < 64){
    unsigned long long prev = 0;
    for (int r = 0; r < m; r++){
      unsigned long long best = ~0ULL;
      if (L <= 256){
        for (int j = t; j < L; j += 64){
          unsigned long long pk = (((unsigned long long)candk[j]) << 32) | (unsigned)candi[j];
          if (pk > prev && pk < best) best = pk;
        }
      } else {
        for (int j = 0; j < 128; j++){
          int n = t + j * 64;
          unsigned u = key[n];
          if ((u >> 16) == T16){
            unsigned long long pk = (((unsigned long long)u) << 32) | (unsigned)n;
            if (pk > prev && pk < best) best = pk;
          }
        }
      }
#pragma unroll
      for (int off = 32; off > 0; off >>= 1){
        unsigned long long o = __shfl_down(best, off, 64);
        if (o < best) best = o;
      }
      best = __shfl(best, 0, 64);
      if (t == 0) s_sel[c01 + r] = (int)(best & 0xFFFFFFFFu);
      prev = best;
    }
  }
  __syncthreads();
  if (t < NSAMPLE) ws_idx[(size_t)q * NSAMPLE + t] = s_sel[t];
}

// ---------------------------------------------------------------------------
// 5. gather + WeightNet + per-point aggregation -> Agg[16384][4160] bf16
// ---------------------------------------------------------------------------
__global__ __launch_bounds__(256) void agg_kernel(
    const float* __restrict__ xyz, const float* __restrict__ newxyz,
    const int* __restrict__ ws_idx, const unsigned short* __restrict__ ptsT,
    const float* __restrict__ w1, const float* __restrict__ b1,
    const float* __restrict__ w2, const float* __restrict__ b2,
    const float* __restrict__ w3, const float* __restrict__ b3,
    unsigned short* __restrict__ agg){
  __shared__ float feat[32][257];          // padded: (row + c) % 32 distinct
  __shared__ float __align__(16) wgt[32][16];
  __shared__ float xyzn[32][4];
  __shared__ int nid[32];
  const int q = blockIdx.x;
  const int b = q >> 11;
  const int t = threadIdx.x;
  if (t < 32) nid[t] = ws_idx[(size_t)q * NSAMPLE + t];
  __syncthreads();
  if (t < 32){
    int n = nid[t];
    const float* xp = xyz + (size_t)b * 3 * NN;
    float qx = newxyz[q * 3], qy = newxyz[q * 3 + 1], qz = newxyz[q * 3 + 2];
    float xn = xp[n] - qx, yn = xp[NN + n] - qy, zn = xp[2 * NN + n] - qz;
    xyzn[t][0] = xn; xyzn[t][1] = yn; xyzn[t][2] = zn;
    float h1[8], h2[8];
#pragma unroll
    for (int i = 0; i < 8; i++)
      h1[i] = fmaxf(0.f, w1[i * 3] * xn + w1[i * 3 + 1] * yn + w1[i * 3 + 2] * zn + b1[i]);
#pragma unroll
    for (int i = 0; i < 8; i++){
      float a = b2[i];
#pragma unroll
      for (int j = 0; j < 8; j++) a += w2[i * 8 + j] * h1[j];
      h2[i] = fmaxf(0.f, a);
    }
#pragma unroll
    for (int i = 0; i < 16; i++){
      float a = b3[i];
#pragma unroll
      for (int j = 0; j < 8; j++) a += w3[i * 8 + j] * h2[j];
      wgt[t][i] = fmaxf(0.f, a);
    }
  }
  // stage 32 neighbor feature rows (bf16 -> f32 LDS). 1024 16B-chunks total.
#pragma unroll
  for (int j = 0; j < 4; j++){
    int c = t + 256 * j;
    int row = c >> 5, col = c & 31;
    const uint4* src = (const uint4*)(ptsT + ((size_t)b * NN + nid[row]) * ND) + col;
    uint4 v = *src;
    float* dstf = &feat[row][col * 8];
    dstf[0] = bf2f((unsigned short)(v.x & 0xFFFF)); dstf[1] = bf2f((unsigned short)(v.x >> 16));
    dstf[2] = bf2f((unsigned short)(v.y & 0xFFFF)); dstf[3] = bf2f((unsigned short)(v.y >> 16));
    dstf[4] = bf2f((unsigned short)(v.z & 0xFFFF)); dstf[5] = bf2f((unsigned short)(v.z >> 16));
    dstf[6] = bf2f((unsigned short)(v.w & 0xFFFF)); dstf[7] = bf2f((unsigned short)(v.w >> 16));
  }
  __syncthreads();
  for (int c = t; c < INCH; c += 256){
    const float* npb; int stride;
    if (c < 3){ npb = &xyzn[0][c]; stride = 4; }
    else      { npb = &feat[0][c - 3]; stride = 257; }
    float acc[16];
#pragma unroll
    for (int i = 0; i < 16; i++) acc[i] = 0.f;
    for (int k = 0; k < 32; k++){
      float v = npb[k * stride];
      const float4v* wr = (const float4v*)(&wgt[k][0]);
      float4v a0 = wr[0], a1 = wr[1], a2 = wr[2], a3 = wr[3];
      acc[0]  += v * a0[0]; acc[1]  += v * a0[1]; acc[2]  += v * a0[2]; acc[3]  += v * a0[3];
      acc[4]  += v * a1[0]; acc[5]  += v * a1[1]; acc[6]  += v * a1[2]; acc[7]  += v * a1[3];
      acc[8]  += v * a2[0]; acc[9]  += v * a2[1]; acc[10] += v * a2[2]; acc[11] += v * a2[3];
      acc[12] += v * a3[0]; acc[13] += v * a3[1]; acc[14] += v * a3[2]; acc[15] += v * a3[3];
    }
    unsigned r[8];
#pragma unroll
    for (int p = 0; p < 8; p++)
      r[p] = (unsigned)f2bf(acc[2 * p]) | ((unsigned)f2bf(acc[2 * p + 1]) << 16);
    uint4* dst = (uint4*)(agg + (size_t)q * KPAD + c * WNET);
    uint4 v0 = {r[0], r[1], r[2], r[3]};
    uint4 v1 = {r[4], r[5], r[6], r[7]};
    dst[0] = v0; dst[1] = v1;
  }
  if (t == 3){   // zero the K pad (ws is poisoned 0xAA)
    uint4 z = {0, 0, 0, 0};
    uint4* dst = (uint4*)(agg + (size_t)q * KPAD + WNET * INCH);
    dst[0] = z; dst[1] = z;
  }
}

// ---------------------------------------------------------------------------
// 6. GEMM: Out[16384,512] = Agg[16384,4160] * lin_w[512,4160]^T (both bf16,
//    K-contiguous), + bias, LeakyReLU, transposed store to [B,512,2048].
// ---------------------------------------------------------------------------
#define BM 128
#define BN 128
#define BK 64
__global__ __launch_bounds__(256) void gemm_kernel(
    const unsigned short* __restrict__ A, const unsigned short* __restrict__ W,
    const float* __restrict__ bias, float* __restrict__ out1){
  __shared__ short __align__(16) As[BM * BK];
  __shared__ short __align__(16) Ws[BN * BK];
  const int t = threadIdx.x;
  const int m0 = blockIdx.x * BM;
  const int n0 = blockIdx.y * BN;
  const int wave = t >> 6, lane = t & 63;
  const int wm = (wave >> 1) * 64, wn = (wave & 1) * 64;
  const int lrow = lane & 15, quad = lane >> 4;
  float4v acc[4][4];
#pragma unroll
  for (int i = 0; i < 4; i++)
#pragma unroll
    for (int j = 0; j < 4; j++) acc[i][j] = (float4v){0.f, 0.f, 0.f, 0.f};

  for (int k0 = 0; k0 < KPAD; k0 += BK){
#pragma unroll
    for (int j = 0; j < 4; j++){            // stage A tile: 1024 16B chunks
      int chunk = t + 256 * j;
      int row = chunk >> 3, c = chunk & 7;
      uint4 v = *(const uint4*)(A + (size_t)(m0 + row) * KPAD + k0 + c * 8);
      *(uint4*)&As[chunk * 8] = v;
    }
#pragma unroll
    for (int j = 0; j < 4; j++){            // stage W tile
      int chunk = t + 256 * j;
      int row = chunk >> 3, c = chunk & 7;
      uint4 v = *(const uint4*)(W + (size_t)(n0 + row) * KPAD + k0 + c * 8);
      *(uint4*)&Ws[chunk * 8] = v;
    }
    __syncthreads();
#pragma unroll
    for (int kk = 0; kk < 2; kk++){
      short8 a[4], w[4];
      int kof = kk * 32 + quad * 8;
#pragma unroll
      for (int i = 0; i < 4; i++){
        a[i] = *(const short8*)&As[(wm + i * 16 + lrow) * BK + kof];
        w[i] = *(const short8*)&Ws[(wn + i * 16 + lrow) * BK + kof];
      }
#pragma unroll
      for (int i = 0; i < 4; i++)
#pragma unroll
        for (int j = 0; j < 4; j++)
          acc[i][j] = __builtin_amdgcn_mfma_f32_16x16x32_bf16(a[i], w[j], acc[i][j], 0, 0, 0);
    }
    __syncthreads();
  }
  // epilogue: C row = m (quad*4+reg), col = n (lane&15)
#pragma unroll
  for (int i = 0; i < 4; i++){
#pragma unroll
    for (int j = 0; j < 4; j++){
      int m = m0 + wm + i * 16 + quad * 4;
      int n = n0 + wn + j * 16 + lrow;
      float bv = bias[n];
      int bb = m >> 11, s = m & 2047;
      float* dst = out1 + ((size_t)bb * OUTCH + n) * NPOINT + s;
      float4v v = acc[i][j];
      float4v r;
#pragma unroll
      for (int e = 0; e < 4; e++){
        float x = v[e] + bv;
        r[e] = x > 0.f ? x : 0.1f * x;
      }
      *(float4v*)dst = r;
    }
  }
}

// ---------------------------------------------------------------------------
extern "C" void kernel_launch(void* const* d_in, const int* in_sizes, int n_in,
                              void* d_out, int out_size, void* d_ws, size_t ws_size,
                              hipStream_t stream) {
  const float* xyz    = (const float*)d_in[0];
  const float* points = (const float*)d_in[1];
  const float* w1 = (const float*)d_in[2];
  const float* b1 = (const float*)d_in[3];
  const float* w2 = (const float*)d_in[4];
  const float* b2 = (const float*)d_in[5];
  const float* w3 = (const float*)d_in[6];
  const float* b3 = (const float*)d_in[7];
  const float* lin_w = (const float*)d_in[8];
  const float* lin_b = (const float*)d_in[9];

  float* out0 = (float*)d_out;                       // [8,3,2048]
  float* out1 = out0 + (size_t)NB * 3 * NPOINT;      // [8,512,2048]
  float* out2 = out1 + (size_t)NB * OUTCH * NPOINT;  // [8,2048] fps idx (as f32)

  char* ws = (char*)d_ws;
  float* ws_newxyz = (float*)ws;                                   size_t o = (size_t)NB * NPOINT * 3 * 4;
  int* ws_idx = (int*)(ws + o);                                    o += (size_t)NB * NPOINT * NSAMPLE * 4;
  unsigned short* ws_ptsT = (unsigned short*)(ws + o);             o += (size_t)NB * NN * ND * 2;
  unsigned short* ws_lw = (unsigned short*)(ws + o);               o += (size_t)OUTCH * KPAD * 2;
  unsigned short* ws_agg = (unsigned short*)(ws + o);              // 16384 * 4160 * 2

  transpose_points<<<dim3(NN / 64, ND / 64, NB), dim3(64, 16), 0, stream>>>(points, ws_ptsT);
  convert_linw<<<(OUTCH * KPAD + 255) / 256, 256, 0, stream>>>(lin_w, ws_lw);
  fps_kernel<<<NB, 1024, 0, stream>>>(xyz, out0, out2, ws_newxyz);
  knn_kernel<<<NB * NPOINT, 256, 0, stream>>>(xyz, ws_newxyz, ws_idx);
  agg_kernel<<<NB * NPOINT, 256, 0, stream>>>(xyz, ws_newxyz, ws_idx, ws_ptsT,
                                              w1, b1, w2, b2, w3, b3, ws_agg);
  gemm_kernel<<<dim3(NB * NPOINT / BM, OUTCH / BN), 256, 0, stream>>>(ws_agg, ws_lw, lin_b, out1);
}

// Round 2
// 4131.115 us; speedup vs baseline: 1.1333x; 1.1333x over previous
//
#include <hip/hip_runtime.h>

#define NB 8
#define NN 8192
#define ND 256
#define NPOINT 2048
#define NSAMPLE 32
#define WNET 16
#define INCH 259          // 3 + 256
#define OUTCH 512
#define KPAD 4160         // 259*16 = 4144 padded to 4160 (= 65*64)

typedef short short8 __attribute__((ext_vector_type(8)));
typedef float float4v __attribute__((ext_vector_type(4)));
typedef unsigned long long u64;

__device__ __forceinline__ unsigned short f2bf(float x){
  unsigned u = __float_as_uint(x);
  u = (u + 0x7FFFu + ((u >> 16) & 1u)) >> 16;
  return (unsigned short)u;
}
__device__ __forceinline__ float bf2f(unsigned short v){
  return __uint_as_float(((unsigned)v) << 16);
}

// ---------------------------------------------------------------------------
// 0. Morton sort: per batch, bitonic sort 8192 points by 30-bit Morton key.
//    Outputs sorted coords (exact copies) + original indices.
// ---------------------------------------------------------------------------
__device__ __forceinline__ unsigned p1b2(unsigned v){
  v &= 0x3FFu;
  v = (v | (v << 16)) & 0x030000FFu;
  v = (v | (v << 8))  & 0x0300F00Fu;
  v = (v | (v << 4))  & 0x030C30C3u;
  v = (v | (v << 2))  & 0x09249249u;
  return v;
}

__global__ __launch_bounds__(1024) void morton_sort_kernel(
    const float* __restrict__ xyz, float* __restrict__ sx, float* __restrict__ sy,
    float* __restrict__ sz, int* __restrict__ sorig){
  __shared__ u64 arr[NN];          // 64 KB
  const int b = blockIdx.x, t = threadIdx.x;
  const float* xp = xyz + (size_t)b * 3 * NN;
#pragma unroll
  for (int j = 0; j < 8; j++){
    int n = t + j * 1024;
    float x = xp[n], y = xp[NN + n], z = xp[2 * NN + n];
    // N(0,1) coords: fixed [-6,6] range for quantization (clamp outliers; only
    // affects ordering quality, never correctness).
    unsigned qx = (unsigned)fminf(1023.f, fmaxf(0.f, (x + 6.f) * 85.25f));
    unsigned qy = (unsigned)fminf(1023.f, fmaxf(0.f, (y + 6.f) * 85.25f));
    unsigned qz = (unsigned)fminf(1023.f, fmaxf(0.f, (z + 6.f) * 85.25f));
    unsigned key = (p1b2(qz) << 2) | (p1b2(qy) << 1) | p1b2(qx);
    arr[n] = (((u64)key) << 13) | (unsigned)n;
  }
  __syncthreads();
  for (int k = 2; k <= NN; k <<= 1){
    for (int j = k >> 1; j >= 1; j >>= 1){
#pragma unroll
      for (int pi = 0; pi < 4; pi++){
        int p = t + pi * 1024;
        int lo = ((p & ~(j - 1)) << 1) | (p & (j - 1));
        int hi = lo | j;
        bool asc = (lo & k) == 0;
        u64 a = arr[lo], c = arr[hi];
        if (asc ? (a > c) : (c > a)){ arr[lo] = c; arr[hi] = a; }
      }
      __syncthreads();
    }
  }
#pragma unroll
  for (int j = 0; j < 8; j++){
    int n = t + j * 1024;
    int orig = (int)(arr[n] & 8191u);
    sx[(size_t)b * NN + n] = xp[orig];
    sy[(size_t)b * NN + n] = xp[NN + orig];
    sz[(size_t)b * NN + n] = xp[2 * NN + orig];
    sorig[(size_t)b * NN + n] = orig;
  }
}

// ---------------------------------------------------------------------------
// 1. FPS with conservative geometric screening.
//    Lane owns 8 Morton-contiguous points + bounding sphere. Chunk skipped iff
//    |c-cc|^2 >= (sqrt(lane_max_ld)*1.001 + R)^2  (guarantees NO ld changes,
//    margins dwarf fp rounding -> index sequence bit-identical to reference).
//    Distance math identical to numpy: (dx*dx+dy*dy)+dz*dz, contract off.
// ---------------------------------------------------------------------------
__global__ __launch_bounds__(1024) void fps_kernel(
    const float* __restrict__ sxg, const float* __restrict__ syg,
    const float* __restrict__ szg, const int* __restrict__ sorigg,
    float* __restrict__ out0, float* __restrict__ out2, float* __restrict__ wnew){
#pragma clang fp contract(off)
  __shared__ float sx[NN], sy[NN], sz[NN];    // 96 KB
  __shared__ u64 red[2][16];
  __shared__ int s_pos0;
  const int b = blockIdx.x, t = threadIdx.x;
  const int lane = t & 63, w = t >> 6;
  const int base = w * 512 + lane * 8;
  const float* gx = sxg + (size_t)b * NN;
  const float* gy = syg + (size_t)b * NN;
  const float* gz = szg + (size_t)b * NN;
  const int*   go = sorigg + (size_t)b * NN;

  float x[8], y[8], z[8], ld[8]; int so[8];
#pragma unroll
  for (int j = 0; j < 8; j++){
    int n = base + j;
    x[j] = gx[n]; y[j] = gy[n]; z[j] = gz[n]; so[j] = go[n];
    sx[n] = x[j]; sy[n] = y[j]; sz[n] = z[j];
    if (so[j] == 0) s_pos0 = n;
    ld[j] = 1e10f;
  }
  // chunk bounding sphere (center = AABB mid, radius inflated for fp safety)
  float mnx = x[0], mxx = x[0], mny = y[0], mxy = y[0], mnz = z[0], mxz = z[0];
#pragma unroll
  for (int j = 1; j < 8; j++){
    mnx = fminf(mnx, x[j]); mxx = fmaxf(mxx, x[j]);
    mny = fminf(mny, y[j]); mxy = fmaxf(mxy, y[j]);
    mnz = fminf(mnz, z[j]); mxz = fmaxf(mxz, z[j]);
  }
  const float ccx = (mnx + mxx) * 0.5f, ccy = (mny + mxy) * 0.5f, ccz = (mnz + mxz) * 0.5f;
  float R2 = 0.f;
#pragma unroll
  for (int j = 0; j < 8; j++){
    float dx = x[j] - ccx, dy = y[j] - ccy, dz = z[j] - ccz;
    R2 = fmaxf(R2, (dx * dx + dy * dy) + dz * dz);
  }
  const float R = sqrtf(R2) * 1.001f + 1e-7f;
  float thr = 3e38f;            // force compute on first iteration
  u64 wkey = 0;                 // cached wave winner (valid on lane 0)
  __syncthreads();

  int pos = s_pos0;
  float cx = sx[pos], cy = sy[pos], cz = sz[pos];
  if (t == 0){
    out2[b * NPOINT] = 0.0f;
    out0[(size_t)b * 3 * NPOINT + 0]          = cx;
    out0[(size_t)b * 3 * NPOINT + NPOINT]     = cy;
    out0[(size_t)b * 3 * NPOINT + 2 * NPOINT] = cz;
    wnew[(size_t)b * NPOINT * 3 + 0] = cx;
    wnew[(size_t)b * NPOINT * 3 + 1] = cy;
    wnew[(size_t)b * NPOINT * 3 + 2] = cz;
  }

  for (int i = 1; i < NPOINT; i++){
    float qdx = cx - ccx, qdy = cy - ccy, qdz = cz - ccz;
    float q = (qdx * qdx + qdy * qdy) + qdz * qdz;
    if (__any(q < thr)){
      float bv = -1.f; int bo = 0, bp = 0;
#pragma unroll
      for (int j = 0; j < 8; j++){
        float dx = x[j] - cx, dy = y[j] - cy, dz = z[j] - cz;
        float d  = (dx * dx + dy * dy) + dz * dz;     // numpy order, no fma
        float nd = fminf(ld[j], d);
        ld[j] = nd;
        bool better = (nd > bv) || (nd == bv && so[j] < bo);
        bv = better ? nd : bv;
        bo = better ? so[j] : bo;
        bp = better ? (base + j) : bp;
      }
      u64 k2 = (((u64)__float_as_uint(bv)) << 26) | (((u64)(8191 - bo)) << 13) | (unsigned)bp;
      float sr = sqrtf(bv) * 1.001f + R;
      thr = sr * sr;
#pragma unroll
      for (int off = 32; off > 0; off >>= 1){
        u64 o = __shfl_down(k2, off, 64);
        if (o > k2) k2 = o;
      }
      wkey = k2;                                      // lane 0 holds wave max
    }
    if (lane == 0) red[i & 1][w] = wkey;
    __syncthreads();
    u64 v = red[i & 1][lane & 15];
#pragma unroll
    for (int off = 8; off > 0; off >>= 1){
      u64 o = __shfl_xor(v, off, 64);
      if (o > v) v = o;
    }
    pos = (int)(v & 8191u);
    cx = sx[pos]; cy = sy[pos]; cz = sz[pos];
    if (t == 0){
      int orig = 8191 - (int)((v >> 13) & 8191u);
      out2[b * NPOINT + i] = (float)orig;
      out0[(size_t)b * 3 * NPOINT + i]              = cx;
      out0[(size_t)b * 3 * NPOINT + NPOINT + i]     = cy;
      out0[(size_t)b * 3 * NPOINT + 2 * NPOINT + i] = cz;
      float* wp = wnew + ((size_t)b * NPOINT + i) * 3;
      wp[0] = cx; wp[1] = cy; wp[2] = cz;
    }
  }
}

// ---------------------------------------------------------------------------
// 2. transpose points [B,256,8192] f32 -> [B,8192,256] bf16
// ---------------------------------------------------------------------------
__global__ __launch_bounds__(1024) void transpose_points(
    const float* __restrict__ pts, unsigned short* __restrict__ ptsT){
  __shared__ float tile[64][65];
  const int b  = blockIdx.z;
  const int n0 = blockIdx.x * 64;
  const int d0 = blockIdx.y * 64;
  const int tx = threadIdx.x, ty = threadIdx.y;
  const float* src = pts + ((size_t)b * ND + d0) * NN + n0;
#pragma unroll
  for (int j = 0; j < 4; j++){
    int d = ty + j * 16;
    tile[d][tx] = src[(size_t)d * NN + tx];
  }
  __syncthreads();
  unsigned short* dst = ptsT + ((size_t)b * NN + n0) * ND + d0;
#pragma unroll
  for (int j = 0; j < 4; j++){
    int n = ty + j * 16;
    dst[(size_t)n * ND + tx] = f2bf(tile[tx][n]);
  }
}

// ---------------------------------------------------------------------------
// 3. lin_w [512,4144] f32 -> [512,4160] bf16 (pad zero)
// ---------------------------------------------------------------------------
__global__ __launch_bounds__(256) void convert_linw(
    const float* __restrict__ lw, unsigned short* __restrict__ out){
  int i = blockIdx.x * 256 + threadIdx.x;
  if (i >= OUTCH * KPAD) return;
  int o = i / KPAD, f = i - o * KPAD;
  float v = (f < WNET * INCH) ? lw[(size_t)o * (WNET * INCH) + f] : 0.f;
  out[i] = f2bf(v);
}

// ---------------------------------------------------------------------------
// 4. kNN: one 256-thread WG per query. radix-select rank-32 threshold,
//    stable (key,idx) tie-break for boundary elements.
// ---------------------------------------------------------------------------
__device__ __forceinline__ void find_bin64(const unsigned* hist, unsigned r,
                                           unsigned* outB, unsigned* outC, int lane){
  unsigned h0 = hist[lane * 4 + 0], h1 = hist[lane * 4 + 1];
  unsigned h2 = hist[lane * 4 + 2], h3 = hist[lane * 4 + 3];
  unsigned s4 = h0 + h1 + h2 + h3;
  unsigned sc = s4;
#pragma unroll
  for (int off = 1; off < 64; off <<= 1){
    unsigned o = __shfl_up(sc, off, 64);
    if (lane >= off) sc += o;
  }
  unsigned cum = sc - s4;
  if (cum < r && cum + h0 >= r){ *outB = lane * 4 + 0; *outC = cum; } cum += h0;
  if (cum < r && cum + h1 >= r){ *outB = lane * 4 + 1; *outC = cum; } cum += h1;
  if (cum < r && cum + h2 >= r){ *outB = lane * 4 + 2; *outC = cum; } cum += h2;
  if (cum < r && cum + h3 >= r){ *outB = lane * 4 + 3; *outC = cum; } cum += h3;
}

__global__ __launch_bounds__(256) void knn_kernel(const float* __restrict__ xyz,
    const float* __restrict__ newxyz, int* __restrict__ ws_idx){
  __shared__ unsigned key[NN];
  __shared__ unsigned hist[256];
  __shared__ int s_sel[48];
  __shared__ unsigned candk[256];
  __shared__ int candi[256];
  __shared__ int s_selcnt, s_candcnt;
  __shared__ unsigned s_info[4];
  const int q = blockIdx.x;
  const int b = q >> 11;
  const int t = threadIdx.x;
  const float* xp = xyz + (size_t)b * 3 * NN;
  float qx = newxyz[q * 3], qy = newxyz[q * 3 + 1], qz = newxyz[q * 3 + 2];
  float qq = qx * qx + qy * qy + qz * qz;
#pragma unroll 4
  for (int j = 0; j < 32; j++){
    int n = t + j * 256;
    float px = xp[n], py = xp[NN + n], pz = xp[2 * NN + n];
    float pp = px * px + py * py + pz * pz;
    float d  = qq + pp - 2.f * (qx * px + qy * py + qz * pz);
    unsigned u = __float_as_uint(d);
    u ^= (u & 0x80000000u) ? 0xFFFFFFFFu : 0x80000000u;
    key[n] = u;
  }
  hist[t] = 0;
  if (t == 0){ s_selcnt = 0; s_candcnt = 0; }
  __syncthreads();
#pragma unroll 4
  for (int j = 0; j < 32; j++){
    int n = t + j * 256;
    atomicAdd(&hist[key[n] >> 24], 1u);
  }
  __syncthreads();
  if (t < 64) find_bin64(hist, NSAMPLE, &s_info[0], &s_info[1], t);
  __syncthreads();
  unsigned B1 = s_info[0], c0 = s_info[1];
  hist[t] = 0;
  __syncthreads();
#pragma unroll 4
  for (int j = 0; j < 32; j++){
    int n = t + j * 256;
    unsigned u = key[n];
    if ((u >> 24) == B1) atomicAdd(&hist[(u >> 16) & 0xFFu], 1u);
  }
  __syncthreads();
  if (t < 64) find_bin64(hist, NSAMPLE - c0, &s_info[2], &s_info[3], t);
  __syncthreads();
  unsigned T16 = (B1 << 8) | s_info[2];
  int c01 = (int)(c0 + s_info[3]);
#pragma unroll 4
  for (int j = 0; j < 32; j++){
    int n = t + j * 256;
    unsigned k16 = key[n] >> 16;
    if (k16 < T16){
      int p = atomicAdd(&s_selcnt, 1);
      s_sel[p] = n;
    } else if (k16 == T16){
      int p = atomicAdd(&s_candcnt, 1);
      if (p < 256){ candk[p] = key[n]; candi[p] = n; }
    }
  }
  __syncthreads();
  const int m = NSAMPLE - c01;
  const int L = s_candcnt;
  if (t < 64){
    u64 prev = 0;
    for (int r = 0; r < m; r++){
      u64 best = ~0ULL;
      if (L <= 256){
        for (int j = t; j < L; j += 64){
          u64 pk = (((u64)candk[j]) << 32) | (unsigned)candi[j];
          if (pk > prev && pk < best) best = pk;
        }
      } else {
        for (int j = 0; j < 128; j++){
          int n = t + j * 64;
          unsigned u = key[n];
          if ((u >> 16) == T16){
            u64 pk = (((u64)u) << 32) | (unsigned)n;
            if (pk > prev && pk < best) best = pk;
          }
        }
      }
#pragma unroll
      for (int off = 32; off > 0; off >>= 1){
        u64 o = __shfl_down(best, off, 64);
        if (o < best) best = o;
      }
      best = __shfl(best, 0, 64);
      if (t == 0) s_sel[c01 + r] = (int)(best & 0xFFFFFFFFu);
      prev = best;
    }
  }
  __syncthreads();
  if (t < NSAMPLE) ws_idx[(size_t)q * NSAMPLE + t] = s_sel[t];
}

// ---------------------------------------------------------------------------
// 5. gather + WeightNet + per-point aggregation -> Agg[16384][4160] bf16
// ---------------------------------------------------------------------------
__global__ __launch_bounds__(256) void agg_kernel(
    const float* __restrict__ xyz, const float* __restrict__ newxyz,
    const int* __restrict__ ws_idx, const unsigned short* __restrict__ ptsT,
    const float* __restrict__ w1, const float* __restrict__ b1,
    const float* __restrict__ w2, const float* __restrict__ b2,
    const float* __restrict__ w3, const float* __restrict__ b3,
    unsigned short* __restrict__ agg){
  __shared__ float feat[32][257];
  __shared__ float __align__(16) wgt[32][16];
  __shared__ float xyzn[32][4];
  __shared__ int nid[32];
  const int q = blockIdx.x;
  const int b = q >> 11;
  const int t = threadIdx.x;
  if (t < 32) nid[t] = ws_idx[(size_t)q * NSAMPLE + t];
  __syncthreads();
  if (t < 32){
    int n = nid[t];
    const float* xp = xyz + (size_t)b * 3 * NN;
    float qx = newxyz[q * 3], qy = newxyz[q * 3 + 1], qz = newxyz[q * 3 + 2];
    float xn = xp[n] - qx, yn = xp[NN + n] - qy, zn = xp[2 * NN + n] - qz;
    xyzn[t][0] = xn; xyzn[t][1] = yn; xyzn[t][2] = zn;
    float h1[8], h2[8];
#pragma unroll
    for (int i = 0; i < 8; i++)
      h1[i] = fmaxf(0.f, w1[i * 3] * xn + w1[i * 3 + 1] * yn + w1[i * 3 + 2] * zn + b1[i]);
#pragma unroll
    for (int i = 0; i < 8; i++){
      float a = b2[i];
#pragma unroll
      for (int j = 0; j < 8; j++) a += w2[i * 8 + j] * h1[j];
      h2[i] = fmaxf(0.f, a);
    }
#pragma unroll
    for (int i = 0; i < 16; i++){
      float a = b3[i];
#pragma unroll
      for (int j = 0; j < 8; j++) a += w3[i * 8 + j] * h2[j];
      wgt[t][i] = fmaxf(0.f, a);
    }
  }
#pragma unroll
  for (int j = 0; j < 4; j++){
    int c = t + 256 * j;
    int row = c >> 5, col = c & 31;
    const uint4* src = (const uint4*)(ptsT + ((size_t)b * NN + nid[row]) * ND) + col;
    uint4 v = *src;
    float* dstf = &feat[row][col * 8];
    dstf[0] = bf2f((unsigned short)(v.x & 0xFFFF)); dstf[1] = bf2f((unsigned short)(v.x >> 16));
    dstf[2] = bf2f((unsigned short)(v.y & 0xFFFF)); dstf[3] = bf2f((unsigned short)(v.y >> 16));
    dstf[4] = bf2f((unsigned short)(v.z & 0xFFFF)); dstf[5] = bf2f((unsigned short)(v.z >> 16));
    dstf[6] = bf2f((unsigned short)(v.w & 0xFFFF)); dstf[7] = bf2f((unsigned short)(v.w >> 16));
  }
  __syncthreads();
  for (int c = t; c < INCH; c += 256){
    const float* npb; int stride;
    if (c < 3){ npb = &xyzn[0][c]; stride = 4; }
    else      { npb = &feat[0][c - 3]; stride = 257; }
    float acc[16];
#pragma unroll
    for (int i = 0; i < 16; i++) acc[i] = 0.f;
    for (int k = 0; k < 32; k++){
      float v = npb[k * stride];
      const float4v* wr = (const float4v*)(&wgt[k][0]);
      float4v a0 = wr[0], a1 = wr[1], a2 = wr[2], a3 = wr[3];
      acc[0]  += v * a0[0]; acc[1]  += v * a0[1]; acc[2]  += v * a0[2]; acc[3]  += v * a0[3];
      acc[4]  += v * a1[0]; acc[5]  += v * a1[1]; acc[6]  += v * a1[2]; acc[7]  += v * a1[3];
      acc[8]  += v * a2[0]; acc[9]  += v * a2[1]; acc[10] += v * a2[2]; acc[11] += v * a2[3];
      acc[12] += v * a3[0]; acc[13] += v * a3[1]; acc[14] += v * a3[2]; acc[15] += v * a3[3];
    }
    unsigned r[8];
#pragma unroll
    for (int p = 0; p < 8; p++)
      r[p] = (unsigned)f2bf(acc[2 * p]) | ((unsigned)f2bf(acc[2 * p + 1]) << 16);
    uint4* dst = (uint4*)(agg + (size_t)q * KPAD + c * WNET);
    uint4 v0 = {r[0], r[1], r[2], r[3]};
    uint4 v1 = {r[4], r[5], r[6], r[7]};
    dst[0] = v0; dst[1] = v1;
  }
  if (t == 3){
    uint4 z = {0, 0, 0, 0};
    uint4* dst = (uint4*)(agg + (size_t)q * KPAD + WNET * INCH);
    dst[0] = z; dst[1] = z;
  }
}

// ---------------------------------------------------------------------------
// 6. GEMM: Out[16384,512] = Agg[16384,4160] * lin_w[512,4160]^T + bias,
//    LeakyReLU, transposed store to [B,512,2048].
// ---------------------------------------------------------------------------
#define BM 128
#define BN 128
#define BK 64
__global__ __launch_bounds__(256) void gemm_kernel(
    const unsigned short* __restrict__ A, const unsigned short* __restrict__ W,
    const float* __restrict__ bias, float* __restrict__ out1){
  __shared__ short __align__(16) As[BM * BK];
  __shared__ short __align__(16) Ws[BN * BK];
  const int t = threadIdx.x;
  const int m0 = blockIdx.x * BM;
  const int n0 = blockIdx.y * BN;
  const int wave = t >> 6, lane = t & 63;
  const int wm = (wave >> 1) * 64, wn = (wave & 1) * 64;
  const int lrow = lane & 15, quad = lane >> 4;
  float4v acc[4][4];
#pragma unroll
  for (int i = 0; i < 4; i++)
#pragma unroll
    for (int j = 0; j < 4; j++) acc[i][j] = (float4v){0.f, 0.f, 0.f, 0.f};

  for (int k0 = 0; k0 < KPAD; k0 += BK){
#pragma unroll
    for (int j = 0; j < 4; j++){
      int chunk = t + 256 * j;
      int row = chunk >> 3, c = chunk & 7;
      uint4 v = *(const uint4*)(A + (size_t)(m0 + row) * KPAD + k0 + c * 8);
      *(uint4*)&As[chunk * 8] = v;
    }
#pragma unroll
    for (int j = 0; j < 4; j++){
      int chunk = t + 256 * j;
      int row = chunk >> 3, c = chunk & 7;
      uint4 v = *(const uint4*)(W + (size_t)(n0 + row) * KPAD + k0 + c * 8);
      *(uint4*)&Ws[chunk * 8] = v;
    }
    __syncthreads();
#pragma unroll
    for (int kk = 0; kk < 2; kk++){
      short8 a[4], w[4];
      int kof = kk * 32 + quad * 8;
#pragma unroll
      for (int i = 0; i < 4; i++){
        a[i] = *(const short8*)&As[(wm + i * 16 + lrow) * BK + kof];
        w[i] = *(const short8*)&Ws[(wn + i * 16 + lrow) * BK + kof];
      }
#pragma unroll
      for (int i = 0; i < 4; i++)
#pragma unroll
        for (int j = 0; j < 4; j++)
          acc[i][j] = __builtin_amdgcn_mfma_f32_16x16x32_bf16(a[i], w[j], acc[i][j], 0, 0, 0);
    }
    __syncthreads();
  }
#pragma unroll
  for (int i = 0; i < 4; i++){
#pragma unroll
    for (int j = 0; j < 4; j++){
      int m = m0 + wm + i * 16 + quad * 4;
      int n = n0 + wn + j * 16 + lrow;
      float bv = bias[n];
      int bb = m >> 11, s = m & 2047;
      float* dst = out1 + ((size_t)bb * OUTCH + n) * NPOINT + s;
      float4v v = acc[i][j];
      float4v r;
#pragma unroll
      for (int e = 0; e < 4; e++){
        float x = v[e] + bv;
        r[e] = x > 0.f ? x : 0.1f * x;
      }
      *(float4v*)dst = r;
    }
  }
}

// ---------------------------------------------------------------------------
extern "C" void kernel_launch(void* const* d_in, const int* in_sizes, int n_in,
                              void* d_out, int out_size, void* d_ws, size_t ws_size,
                              hipStream_t stream) {
  const float* xyz    = (const float*)d_in[0];
  const float* points = (const float*)d_in[1];
  const float* w1 = (const float*)d_in[2];
  const float* b1 = (const float*)d_in[3];
  const float* w2 = (const float*)d_in[4];
  const float* b2 = (const float*)d_in[5];
  const float* w3 = (const float*)d_in[6];
  const float* b3 = (const float*)d_in[7];
  const float* lin_w = (const float*)d_in[8];
  const float* lin_b = (const float*)d_in[9];

  float* out0 = (float*)d_out;
  float* out1 = out0 + (size_t)NB * 3 * NPOINT;
  float* out2 = out1 + (size_t)NB * OUTCH * NPOINT;

  char* ws = (char*)d_ws;
  float* ws_newxyz = (float*)ws;                                   size_t o = (size_t)NB * NPOINT * 3 * 4;
  int* ws_idx = (int*)(ws + o);                                    o += (size_t)NB * NPOINT * NSAMPLE * 4;
  unsigned short* ws_ptsT = (unsigned short*)(ws + o);             o += (size_t)NB * NN * ND * 2;
  unsigned short* ws_lw = (unsigned short*)(ws + o);               o += (size_t)OUTCH * KPAD * 2;
  unsigned short* ws_agg = (unsigned short*)(ws + o);              o += (size_t)NB * NPOINT * KPAD * 2;
  float* ws_sx = (float*)(ws + o);                                 o += (size_t)NB * NN * 4;
  float* ws_sy = (float*)(ws + o);                                 o += (size_t)NB * NN * 4;
  float* ws_sz = (float*)(ws + o);                                 o += (size_t)NB * NN * 4;
  int*   ws_so = (int*)(ws + o);                                   o += (size_t)NB * NN * 4;

  morton_sort_kernel<<<NB, 1024, 0, stream>>>(xyz, ws_sx, ws_sy, ws_sz, ws_so);
  fps_kernel<<<NB, 1024, 0, stream>>>(ws_sx, ws_sy, ws_sz, ws_so, out0, out2, ws_newxyz);
  transpose_points<<<dim3(NN / 64, ND / 64, NB), dim3(64, 16), 0, stream>>>(points, ws_ptsT);
  convert_linw<<<(OUTCH * KPAD + 255) / 256, 256, 0, stream>>>(lin_w, ws_lw);
  knn_kernel<<<NB * NPOINT, 256, 0, stream>>>(xyz, ws_newxyz, ws_idx);
  agg_kernel<<<NB * NPOINT, 256, 0, stream>>>(xyz, ws_newxyz, ws_idx, ws_ptsT,
                                              w1, b1, w2, b2, w3, b3, ws_agg);
  gemm_kernel<<<dim3(NB * NPOINT / BM, OUTCH / BN), 256, 0, stream>>>(ws_agg, ws_lw, lin_b, out1);
}

// Round 3
// 3574.070 us; speedup vs baseline: 1.3100x; 1.1559x over previous
//
#include <hip/hip_runtime.h>

#define NB 8
#define NN 8192
#define ND 256
#define NPOINT 2048
#define NSAMPLE 32
#define WNET 16
#define INCH 259          // 3 + 256
#define OUTCH 512
#define KPAD 4160         // 259*16 = 4144 padded to 4160 (= 65*64)

typedef short short8 __attribute__((ext_vector_type(8)));
typedef float float4v __attribute__((ext_vector_type(4)));
typedef unsigned long long u64;

__device__ __forceinline__ unsigned short f2bf(float x){
  unsigned u = __float_as_uint(x);
  u = (u + 0x7FFFu + ((u >> 16) & 1u)) >> 16;
  return (unsigned short)u;
}
__device__ __forceinline__ float bf2f(unsigned short v){
  return __uint_as_float(((unsigned)v) << 16);
}

// wave64 max of packed u64 via DPP (VALU-latency, no ds_bpermute).
// Result valid in lane 63. bound_ctrl=1 -> 0-fill (identity for unsigned max).
__device__ __forceinline__ u64 wave_max_dpp(u64 k){
#define DPPSTEP(ctrl) {                                                        \
    unsigned lo = (unsigned)k, hi = (unsigned)(k >> 32);                       \
    unsigned olo = (unsigned)__builtin_amdgcn_update_dpp(0, (int)lo, ctrl, 0xf, 0xf, true); \
    unsigned ohi = (unsigned)__builtin_amdgcn_update_dpp(0, (int)hi, ctrl, 0xf, 0xf, true); \
    u64 o = (((u64)ohi) << 32) | olo;                                          \
    if (o > k) k = o; }
  DPPSTEP(0x111)  // row_shr:1
  DPPSTEP(0x112)  // row_shr:2
  DPPSTEP(0x114)  // row_shr:4
  DPPSTEP(0x118)  // row_shr:8
  DPPSTEP(0x142)  // row_bcast15
  DPPSTEP(0x143)  // row_bcast31
#undef DPPSTEP
  return k;
}

// ---------------------------------------------------------------------------
// 0. Morton sort: per batch, bitonic sort 8192 points by 30-bit Morton key.
// ---------------------------------------------------------------------------
__device__ __forceinline__ unsigned p1b2(unsigned v){
  v &= 0x3FFu;
  v = (v | (v << 16)) & 0x030000FFu;
  v = (v | (v << 8))  & 0x0300F00Fu;
  v = (v | (v << 4))  & 0x030C30C3u;
  v = (v | (v << 2))  & 0x09249249u;
  return v;
}

__global__ __launch_bounds__(1024) void morton_sort_kernel(
    const float* __restrict__ xyz, float* __restrict__ sx, float* __restrict__ sy,
    float* __restrict__ sz, int* __restrict__ sorig){
  __shared__ u64 arr[NN];          // 64 KB
  const int b = blockIdx.x, t = threadIdx.x;
  const float* xp = xyz + (size_t)b * 3 * NN;
#pragma unroll
  for (int j = 0; j < 8; j++){
    int n = t + j * 1024;
    float x = xp[n], y = xp[NN + n], z = xp[2 * NN + n];
    unsigned qx = (unsigned)fminf(1023.f, fmaxf(0.f, (x + 6.f) * 85.25f));
    unsigned qy = (unsigned)fminf(1023.f, fmaxf(0.f, (y + 6.f) * 85.25f));
    unsigned qz = (unsigned)fminf(1023.f, fmaxf(0.f, (z + 6.f) * 85.25f));
    unsigned key = (p1b2(qz) << 2) | (p1b2(qy) << 1) | p1b2(qx);
    arr[n] = (((u64)key) << 13) | (unsigned)n;
  }
  __syncthreads();
  for (int k = 2; k <= NN; k <<= 1){
    for (int j = k >> 1; j >= 1; j >>= 1){
#pragma unroll
      for (int pi = 0; pi < 4; pi++){
        int p = t + pi * 1024;
        int lo = ((p & ~(j - 1)) << 1) | (p & (j - 1));
        int hi = lo | j;
        bool asc = (lo & k) == 0;
        u64 a = arr[lo], c = arr[hi];
        if (asc ? (a > c) : (c > a)){ arr[lo] = c; arr[hi] = a; }
      }
      __syncthreads();
    }
  }
#pragma unroll
  for (int j = 0; j < 8; j++){
    int n = t + j * 1024;
    int orig = (int)(arr[n] & 8191u);
    sx[(size_t)b * NN + n] = xp[orig];
    sy[(size_t)b * NN + n] = xp[NN + orig];
    sz[(size_t)b * NN + n] = xp[2 * NN + orig];
    sorig[(size_t)b * NN + n] = orig;
  }
}

// ---------------------------------------------------------------------------
// 1. FPS: geometric screening + DPP wave-max + LDS u64 atomicMax cross-wave.
//    Distance math identical to numpy: (dx*dx+dy*dy)+dz*dz, contract off.
// ---------------------------------------------------------------------------
__global__ __launch_bounds__(1024) void fps_kernel(
    const float* __restrict__ sxg, const float* __restrict__ syg,
    const float* __restrict__ szg, const int* __restrict__ sorigg,
    float* __restrict__ out0, float* __restrict__ out2, float* __restrict__ wnew){
#pragma clang fp contract(off)
  __shared__ float4v pxyz[NN];     // 128 KB: coords as float4 for 1-read lookup
  __shared__ u64 slot[3];          // rotating winner slots
  __shared__ int s_pos0;
  const int b = blockIdx.x, t = threadIdx.x;
  const int lane = t & 63, w = t >> 6;
  const int base = w * 512 + lane * 8;
  const float* gx = sxg + (size_t)b * NN;
  const float* gy = syg + (size_t)b * NN;
  const float* gz = szg + (size_t)b * NN;
  const int*   go = sorigg + (size_t)b * NN;

  float x[8], y[8], z[8], ld[8]; int so[8];
#pragma unroll
  for (int j = 0; j < 8; j++){
    int n = base + j;
    x[j] = gx[n]; y[j] = gy[n]; z[j] = gz[n]; so[j] = go[n];
    pxyz[n] = (float4v){x[j], y[j], z[j], 0.f};
    if (so[j] == 0) s_pos0 = n;
    ld[j] = 1e10f;
  }
  if (t < 3) slot[t] = 0;
  // chunk bounding sphere (center = AABB mid, radius inflated for fp safety)
  float mnx = x[0], mxx = x[0], mny = y[0], mxy = y[0], mnz = z[0], mxz = z[0];
#pragma unroll
  for (int j = 1; j < 8; j++){
    mnx = fminf(mnx, x[j]); mxx = fmaxf(mxx, x[j]);
    mny = fminf(mny, y[j]); mxy = fmaxf(mxy, y[j]);
    mnz = fminf(mnz, z[j]); mxz = fmaxf(mxz, z[j]);
  }
  const float ccx = (mnx + mxx) * 0.5f, ccy = (mny + mxy) * 0.5f, ccz = (mnz + mxz) * 0.5f;
  float R2 = 0.f;
#pragma unroll
  for (int j = 0; j < 8; j++){
    float dx = x[j] - ccx, dy = y[j] - ccy, dz = z[j] - ccz;
    R2 = fmaxf(R2, (dx * dx + dy * dy) + dz * dz);
  }
  const float R = sqrtf(R2) * 1.001f + 1e-7f;
  float thr = 3e38f;            // force compute on first iteration
  u64 wkey = 0;                 // cached wave winner (valid on lane 63)
  __syncthreads();

  int pos = s_pos0;
  float4v c4 = pxyz[pos];
  float cx = c4[0], cy = c4[1], cz = c4[2];
  if (t == 0){
    out2[b * NPOINT] = 0.0f;
    out0[(size_t)b * 3 * NPOINT + 0]          = cx;
    out0[(size_t)b * 3 * NPOINT + NPOINT]     = cy;
    out0[(size_t)b * 3 * NPOINT + 2 * NPOINT] = cz;
    wnew[(size_t)b * NPOINT * 3 + 0] = cx;
    wnew[(size_t)b * NPOINT * 3 + 1] = cy;
    wnew[(size_t)b * NPOINT * 3 + 2] = cz;
  }

  for (int i = 1; i < NPOINT; i++){
    float qdx = cx - ccx, qdy = cy - ccy, qdz = cz - ccz;
    float q = (qdx * qdx + qdy * qdy) + qdz * qdz;
    if (__any(q < thr)){
      float bv = -1.f; int bo = 0, bp = 0;
#pragma unroll
      for (int j = 0; j < 8; j++){
        float dx = x[j] - cx, dy = y[j] - cy, dz = z[j] - cz;
        float d  = (dx * dx + dy * dy) + dz * dz;     // numpy order, no fma
        float nd = fminf(ld[j], d);
        ld[j] = nd;
        bool better = (nd > bv) || (nd == bv && so[j] < bo);
        bv = better ? nd : bv;
        bo = better ? so[j] : bo;
        bp = better ? (base + j) : bp;
      }
      float sr = sqrtf(bv) * 1.001f + R;
      thr = sr * sr;
      u64 k2 = (((u64)__float_as_uint(bv)) << 26) | (((u64)(8191 - bo)) << 13) | (unsigned)bp;
      wkey = wave_max_dpp(k2);                        // lane 63 holds wave max
    }
    if (lane == 63) atomicMax((u64*)&slot[i % 3], wkey);
    if (t == 0) slot[(i + 1) % 3] = 0;
    __syncthreads();
    u64 v = slot[i % 3];
    pos = (int)(v & 8191u);
    float4v n4 = pxyz[pos];
    cx = n4[0]; cy = n4[1]; cz = n4[2];
    if (t == 0){
      int orig = 8191 - (int)((v >> 13) & 8191u);
      out2[b * NPOINT + i] = (float)orig;
      out0[(size_t)b * 3 * NPOINT + i]              = cx;
      out0[(size_t)b * 3 * NPOINT + NPOINT + i]     = cy;
      out0[(size_t)b * 3 * NPOINT + 2 * NPOINT + i] = cz;
      float* wp = wnew + ((size_t)b * NPOINT + i) * 3;
      wp[0] = cx; wp[1] = cy; wp[2] = cz;
    }
  }
}

// ---------------------------------------------------------------------------
// 2. transpose points [B,256,8192] f32 -> [B,8192,256] bf16
// ---------------------------------------------------------------------------
__global__ __launch_bounds__(1024) void transpose_points(
    const float* __restrict__ pts, unsigned short* __restrict__ ptsT){
  __shared__ float tile[64][65];
  const int b  = blockIdx.z;
  const int n0 = blockIdx.x * 64;
  const int d0 = blockIdx.y * 64;
  const int tx = threadIdx.x, ty = threadIdx.y;
  const float* src = pts + ((size_t)b * ND + d0) * NN + n0;
#pragma unroll
  for (int j = 0; j < 4; j++){
    int d = ty + j * 16;
    tile[d][tx] = src[(size_t)d * NN + tx];
  }
  __syncthreads();
  unsigned short* dst = ptsT + ((size_t)b * NN + n0) * ND + d0;
#pragma unroll
  for (int j = 0; j < 4; j++){
    int n = ty + j * 16;
    dst[(size_t)n * ND + tx] = f2bf(tile[tx][n]);
  }
}

// ---------------------------------------------------------------------------
// 3. lin_w [512,4144] f32 -> [512,4160] bf16 (pad zero)
// ---------------------------------------------------------------------------
__global__ __launch_bounds__(256) void convert_linw(
    const float* __restrict__ lw, unsigned short* __restrict__ out){
  int i = blockIdx.x * 256 + threadIdx.x;
  if (i >= OUTCH * KPAD) return;
  int o = i / KPAD, f = i - o * KPAD;
  float v = (f < WNET * INCH) ? lw[(size_t)o * (WNET * INCH) + f] : 0.f;
  out[i] = f2bf(v);
}

// ---------------------------------------------------------------------------
// 4. kNN: one 256-thread WG per query. radix-select rank-32 threshold,
//    stable (key,idx) tie-break for boundary elements.
// ---------------------------------------------------------------------------
__device__ __forceinline__ void find_bin64(const unsigned* hist, unsigned r,
                                           unsigned* outB, unsigned* outC, int lane){
  unsigned h0 = hist[lane * 4 + 0], h1 = hist[lane * 4 + 1];
  unsigned h2 = hist[lane * 4 + 2], h3 = hist[lane * 4 + 3];
  unsigned s4 = h0 + h1 + h2 + h3;
  unsigned sc = s4;
#pragma unroll
  for (int off = 1; off < 64; off <<= 1){
    unsigned o = __shfl_up(sc, off, 64);
    if (lane >= off) sc += o;
  }
  unsigned cum = sc - s4;
  if (cum < r && cum + h0 >= r){ *outB = lane * 4 + 0; *outC = cum; } cum += h0;
  if (cum < r && cum + h1 >= r){ *outB = lane * 4 + 1; *outC = cum; } cum += h1;
  if (cum < r && cum + h2 >= r){ *outB = lane * 4 + 2; *outC = cum; } cum += h2;
  if (cum < r && cum + h3 >= r){ *outB = lane * 4 + 3; *outC = cum; } cum += h3;
}

__global__ __launch_bounds__(256) void knn_kernel(const float* __restrict__ xyz,
    const float* __restrict__ newxyz, int* __restrict__ ws_idx){
  __shared__ unsigned key[NN];
  __shared__ unsigned hist[256];
  __shared__ int s_sel[48];
  __shared__ unsigned candk[256];
  __shared__ int candi[256];
  __shared__ int s_selcnt, s_candcnt;
  __shared__ unsigned s_info[4];
  const int q = blockIdx.x;
  const int b = q >> 11;
  const int t = threadIdx.x;
  const float* xp = xyz + (size_t)b * 3 * NN;
  float qx = newxyz[q * 3], qy = newxyz[q * 3 + 1], qz = newxyz[q * 3 + 2];
  float qq = qx * qx + qy * qy + qz * qz;
#pragma unroll 4
  for (int j = 0; j < 32; j++){
    int n = t + j * 256;
    float px = xp[n], py = xp[NN + n], pz = xp[2 * NN + n];
    float pp = px * px + py * py + pz * pz;
    float d  = qq + pp - 2.f * (qx * px + qy * py + qz * pz);
    unsigned u = __float_as_uint(d);
    u ^= (u & 0x80000000u) ? 0xFFFFFFFFu : 0x80000000u;
    key[n] = u;
  }
  hist[t] = 0;
  if (t == 0){ s_selcnt = 0; s_candcnt = 0; }
  __syncthreads();
#pragma unroll 4
  for (int j = 0; j < 32; j++){
    int n = t + j * 256;
    atomicAdd(&hist[key[n] >> 24], 1u);
  }
  __syncthreads();
  if (t < 64) find_bin64(hist, NSAMPLE, &s_info[0], &s_info[1], t);
  __syncthreads();
  unsigned B1 = s_info[0], c0 = s_info[1];
  hist[t] = 0;
  __syncthreads();
#pragma unroll 4
  for (int j = 0; j < 32; j++){
    int n = t + j * 256;
    unsigned u = key[n];
    if ((u >> 24) == B1) atomicAdd(&hist[(u >> 16) & 0xFFu], 1u);
  }
  __syncthreads();
  if (t < 64) find_bin64(hist, NSAMPLE - c0, &s_info[2], &s_info[3], t);
  __syncthreads();
  unsigned T16 = (B1 << 8) | s_info[2];
  int c01 = (int)(c0 + s_info[3]);
#pragma unroll 4
  for (int j = 0; j < 32; j++){
    int n = t + j * 256;
    unsigned k16 = key[n] >> 16;
    if (k16 < T16){
      int p = atomicAdd(&s_selcnt, 1);
      s_sel[p] = n;
    } else if (k16 == T16){
      int p = atomicAdd(&s_candcnt, 1);
      if (p < 256){ candk[p] = key[n]; candi[p] = n; }
    }
  }
  __syncthreads();
  const int m = NSAMPLE - c01;
  const int L = s_candcnt;
  if (t < 64){
    u64 prev = 0;
    for (int r = 0; r < m; r++){
      u64 best = ~0ULL;
      if (L <= 256){
        for (int j = t; j < L; j += 64){
          u64 pk = (((u64)candk[j]) << 32) | (unsigned)candi[j];
          if (pk > prev && pk < best) best = pk;
        }
      } else {
        for (int j = 0; j < 128; j++){
          int n = t + j * 64;
          unsigned u = key[n];
          if ((u >> 16) == T16){
            u64 pk = (((u64)u) << 32) | (unsigned)n;
            if (pk > prev && pk < best) best = pk;
          }
        }
      }
#pragma unroll
      for (int off = 32; off > 0; off >>= 1){
        u64 o = __shfl_down(best, off, 64);
        if (o < best) best = o;
      }
      best = __shfl(best, 0, 64);
      if (t == 0) s_sel[c01 + r] = (int)(best & 0xFFFFFFFFu);
      prev = best;
    }
  }
  __syncthreads();
  if (t < NSAMPLE) ws_idx[(size_t)q * NSAMPLE + t] = s_sel[t];
}

// ---------------------------------------------------------------------------
// 5. gather + WeightNet + per-point aggregation -> Agg[16384][4160] bf16
// ---------------------------------------------------------------------------
__global__ __launch_bounds__(256) void agg_kernel(
    const float* __restrict__ xyz, const float* __restrict__ newxyz,
    const int* __restrict__ ws_idx, const unsigned short* __restrict__ ptsT,
    const float* __restrict__ w1, const float* __restrict__ b1,
    const float* __restrict__ w2, const float* __restrict__ b2,
    const float* __restrict__ w3, const float* __restrict__ b3,
    unsigned short* __restrict__ agg){
  __shared__ float feat[32][257];
  __shared__ float __align__(16) wgt[32][16];
  __shared__ float xyzn[32][4];
  __shared__ int nid[32];
  const int q = blockIdx.x;
  const int b = q >> 11;
  const int t = threadIdx.x;
  if (t < 32) nid[t] = ws_idx[(size_t)q * NSAMPLE + t];
  __syncthreads();
  if (t < 32){
    int n = nid[t];
    const float* xp = xyz + (size_t)b * 3 * NN;
    float qx = newxyz[q * 3], qy = newxyz[q * 3 + 1], qz = newxyz[q * 3 + 2];
    float xn = xp[n] - qx, yn = xp[NN + n] - qy, zn = xp[2 * NN + n] - qz;
    xyzn[t][0] = xn; xyzn[t][1] = yn; xyzn[t][2] = zn;
    float h1[8], h2[8];
#pragma unroll
    for (int i = 0; i < 8; i++)
      h1[i] = fmaxf(0.f, w1[i * 3] * xn + w1[i * 3 + 1] * yn + w1[i * 3 + 2] * zn + b1[i]);
#pragma unroll
    for (int i = 0; i < 8; i++){
      float a = b2[i];
#pragma unroll
      for (int j = 0; j < 8; j++) a += w2[i * 8 + j] * h1[j];
      h2[i] = fmaxf(0.f, a);
    }
#pragma unroll
    for (int i = 0; i < 16; i++){
      float a = b3[i];
#pragma unroll
      for (int j = 0; j < 8; j++) a += w3[i * 8 + j] * h2[j];
      wgt[t][i] = fmaxf(0.f, a);
    }
  }
#pragma unroll
  for (int j = 0; j < 4; j++){
    int c = t + 256 * j;
    int row = c >> 5, col = c & 31;
    const uint4* src = (const uint4*)(ptsT + ((size_t)b * NN + nid[row]) * ND) + col;
    uint4 v = *src;
    float* dstf = &feat[row][col * 8];
    dstf[0] = bf2f((unsigned short)(v.x & 0xFFFF)); dstf[1] = bf2f((unsigned short)(v.x >> 16));
    dstf[2] = bf2f((unsigned short)(v.y & 0xFFFF)); dstf[3] = bf2f((unsigned short)(v.y >> 16));
    dstf[4] = bf2f((unsigned short)(v.z & 0xFFFF)); dstf[5] = bf2f((unsigned short)(v.z >> 16));
    dstf[6] = bf2f((unsigned short)(v.w & 0xFFFF)); dstf[7] = bf2f((unsigned short)(v.w >> 16));
  }
  __syncthreads();
  for (int c = t; c < INCH; c += 256){
    const float* npb; int stride;
    if (c < 3){ npb = &xyzn[0][c]; stride = 4; }
    else      { npb = &feat[0][c - 3]; stride = 257; }
    float acc[16];
#pragma unroll
    for (int i = 0; i < 16; i++) acc[i] = 0.f;
    for (int k = 0; k < 32; k++){
      float v = npb[k * stride];
      const float4v* wr = (const float4v*)(&wgt[k][0]);
      float4v a0 = wr[0], a1 = wr[1], a2 = wr[2], a3 = wr[3];
      acc[0]  += v * a0[0]; acc[1]  += v * a0[1]; acc[2]  += v * a0[2]; acc[3]  += v * a0[3];
      acc[4]  += v * a1[0]; acc[5]  += v * a1[1]; acc[6]  += v * a1[2]; acc[7]  += v * a1[3];
      acc[8]  += v * a2[0]; acc[9]  += v * a2[1]; acc[10] += v * a2[2]; acc[11] += v * a2[3];
      acc[12] += v * a3[0]; acc[13] += v * a3[1]; acc[14] += v * a3[2]; acc[15] += v * a3[3];
    }
    unsigned r[8];
#pragma unroll
    for (int p = 0; p < 8; p++)
      r[p] = (unsigned)f2bf(acc[2 * p]) | ((unsigned)f2bf(acc[2 * p + 1]) << 16);
    uint4* dst = (uint4*)(agg + (size_t)q * KPAD + c * WNET);
    uint4 v0 = {r[0], r[1], r[2], r[3]};
    uint4 v1 = {r[4], r[5], r[6], r[7]};
    dst[0] = v0; dst[1] = v1;
  }
  if (t == 3){
    uint4 z = {0, 0, 0, 0};
    uint4* dst = (uint4*)(agg + (size_t)q * KPAD + WNET * INCH);
    dst[0] = z; dst[1] = z;
  }
}

// ---------------------------------------------------------------------------
// 6. GEMM: Out[16384,512] = Agg[16384,4160] * lin_w[512,4160]^T + bias,
//    LeakyReLU, transposed store to [B,512,2048].
// ---------------------------------------------------------------------------
#define BM 128
#define BN 128
#define BK 64
__global__ __launch_bounds__(256) void gemm_kernel(
    const unsigned short* __restrict__ A, const unsigned short* __restrict__ W,
    const float* __restrict__ bias, float* __restrict__ out1){
  __shared__ short __align__(16) As[BM * BK];
  __shared__ short __align__(16) Ws[BN * BK];
  const int t = threadIdx.x;
  const int m0 = blockIdx.x * BM;
  const int n0 = blockIdx.y * BN;
  const int wave = t >> 6, lane = t & 63;
  const int wm = (wave >> 1) * 64, wn = (wave & 1) * 64;
  const int lrow = lane & 15, quad = lane >> 4;
  float4v acc[4][4];
#pragma unroll
  for (int i = 0; i < 4; i++)
#pragma unroll
    for (int j = 0; j < 4; j++) acc[i][j] = (float4v){0.f, 0.f, 0.f, 0.f};

  for (int k0 = 0; k0 < KPAD; k0 += BK){
#pragma unroll
    for (int j = 0; j < 4; j++){
      int chunk = t + 256 * j;
      int row = chunk >> 3, c = chunk & 7;
      uint4 v = *(const uint4*)(A + (size_t)(m0 + row) * KPAD + k0 + c * 8);
      *(uint4*)&As[chunk * 8] = v;
    }
#pragma unroll
    for (int j = 0; j < 4; j++){
      int chunk = t + 256 * j;
      int row = chunk >> 3, c = chunk & 7;
      uint4 v = *(const uint4*)(W + (size_t)(n0 + row) * KPAD + k0 + c * 8);
      *(uint4*)&Ws[chunk * 8] = v;
    }
    __syncthreads();
#pragma unroll
    for (int kk = 0; kk < 2; kk++){
      short8 a[4], w[4];
      int kof = kk * 32 + quad * 8;
#pragma unroll
      for (int i = 0; i < 4; i++){
        a[i] = *(const short8*)&As[(wm + i * 16 + lrow) * BK + kof];
        w[i] = *(const short8*)&Ws[(wn + i * 16 + lrow) * BK + kof];
      }
#pragma unroll
      for (int i = 0; i < 4; i++)
#pragma unroll
        for (int j = 0; j < 4; j++)
          acc[i][j] = __builtin_amdgcn_mfma_f32_16x16x32_bf16(a[i], w[j], acc[i][j], 0, 0, 0);
    }
    __syncthreads();
  }
#pragma unroll
  for (int i = 0; i < 4; i++){
#pragma unroll
    for (int j = 0; j < 4; j++){
      int m = m0 + wm + i * 16 + quad * 4;
      int n = n0 + wn + j * 16 + lrow;
      float bv = bias[n];
      int bb = m >> 11, s = m & 2047;
      float* dst = out1 + ((size_t)bb * OUTCH + n) * NPOINT + s;
      float4v v = acc[i][j];
      float4v r;
#pragma unroll
      for (int e = 0; e < 4; e++){
        float x = v[e] + bv;
        r[e] = x > 0.f ? x : 0.1f * x;
      }
      *(float4v*)dst = r;
    }
  }
}

// ---------------------------------------------------------------------------
extern "C" void kernel_launch(void* const* d_in, const int* in_sizes, int n_in,
                              void* d_out, int out_size, void* d_ws, size_t ws_size,
                              hipStream_t stream) {
  const float* xyz    = (const float*)d_in[0];
  const float* points = (const float*)d_in[1];
  const float* w1 = (const float*)d_in[2];
  const float* b1 = (const float*)d_in[3];
  const float* w2 = (const float*)d_in[4];
  const float* b2 = (const float*)d_in[5];
  const float* w3 = (const float*)d_in[6];
  const float* b3 = (const float*)d_in[7];
  const float* lin_w = (const float*)d_in[8];
  const float* lin_b = (const float*)d_in[9];

  float* out0 = (float*)d_out;
  float* out1 = out0 + (size_t)NB * 3 * NPOINT;
  float* out2 = out1 + (size_t)NB * OUTCH * NPOINT;

  char* ws = (char*)d_ws;
  float* ws_newxyz = (float*)ws;                                   size_t o = (size_t)NB * NPOINT * 3 * 4;
  int* ws_idx = (int*)(ws + o);                                    o += (size_t)NB * NPOINT * NSAMPLE * 4;
  unsigned short* ws_ptsT = (unsigned short*)(ws + o);             o += (size_t)NB * NN * ND * 2;
  unsigned short* ws_lw = (unsigned short*)(ws + o);               o += (size_t)OUTCH * KPAD * 2;
  unsigned short* ws_agg = (unsigned short*)(ws + o);              o += (size_t)NB * NPOINT * KPAD * 2;
  float* ws_sx = (float*)(ws + o);                                 o += (size_t)NB * NN * 4;
  float* ws_sy = (float*)(ws + o);                                 o += (size_t)NB * NN * 4;
  float* ws_sz = (float*)(ws + o);                                 o += (size_t)NB * NN * 4;
  int*   ws_so = (int*)(ws + o);                                   o += (size_t)NB * NN * 4;

  morton_sort_kernel<<<NB, 1024, 0, stream>>>(xyz, ws_sx, ws_sy, ws_sz, ws_so);
  fps_kernel<<<NB, 1024, 0, stream>>>(ws_sx, ws_sy, ws_sz, ws_so, out0, out2, ws_newxyz);
  transpose_points<<<dim3(NN / 64, ND / 64, NB), dim3(64, 16), 0, stream>>>(points, ws_ptsT);
  convert_linw<<<(OUTCH * KPAD + 255) / 256, 256, 0, stream>>>(lin_w, ws_lw);
  knn_kernel<<<NB * NPOINT, 256, 0, stream>>>(xyz, ws_newxyz, ws_idx);
  agg_kernel<<<NB * NPOINT, 256, 0, stream>>>(xyz, ws_newxyz, ws_idx, ws_ptsT,
                                              w1, b1, w2, b2, w3, b3, ws_agg);
  gemm_kernel<<<dim3(NB * NPOINT / BM, OUTCH / BN), 256, 0, stream>>>(ws_agg, ws_lw, lin_b, out1);
}